// Round 3
// baseline (2265.994 us; speedup 1.0000x reference)
//
#include <hip/hip_runtime.h>

typedef unsigned short u16;
typedef unsigned int u32;

typedef __bf16 bf16x8 __attribute__((ext_vector_type(8)));
typedef float f32x4 __attribute__((ext_vector_type(4)));

__device__ __forceinline__ float bf2f(u16 u) {
  union { u32 i; float f; } v; v.i = ((u32)u) << 16; return v.f;
}
__device__ __forceinline__ u16 f2bf(float f) {
  union { float f; u32 i; } v; v.f = f;
  u32 r = v.i + 0x7fff + ((v.i >> 16) & 1);
  return (u16)(r >> 16);
}
__device__ __forceinline__ u32 packbf(float a, float b) {
  return (u32)f2bf(a) | ((u32)f2bf(b) << 16);
}

// Detect input dtype from ln1_w (all ones): bf16 word = 0x3F803F80, fp32 = 0x3F800000.
__global__ void detect_k(const u32* __restrict__ w, u32* __restrict__ flag) {
  if (threadIdx.x == 0 && blockIdx.x == 0)
    *flag = (w[0] == 0x3F803F80u) ? 0u : 1u;
}

// ---------------------------------------------------------------------------
// bf16 MFMA GEMM: C[M,N] = A[M,K] * B[N,K]^T, fp32 accum.
// A is ALWAYS internal bf16 (workspace). B is a d_in weight: dual dtype (flag).
// EPI 0: store bf16.
// EPI 1: store fp32 C = acc + R(dual-dtype d_in residual x).
// EPI 2: final: store (flag? fp32 : bf16) C = acc + fp32 R (x1).
// EPI 3: fused SwiGLU: store bf16 C = silu(bf16 R[idx]) * acc  (R may == Cout).
// ---------------------------------------------------------------------------
#define BM 128
#define BN 128
#define BKK 64
#define LDK 72  // padded LDS row stride in u16

template<int EPI>
__global__ __launch_bounds__(256)
void gemm_bt(const u16* __restrict__ A, const void* __restrict__ B,
             void* Cout, const void* R,
             int M, int N, int K, const u32* __restrict__ dflag)
{
  __shared__ u16 sA[BM * LDK];
  __shared__ u16 sB[BN * LDK];
  const u32 f = *dflag;
  const int tid  = threadIdx.x;
  const int bm   = blockIdx.y * BM;
  const int bn   = blockIdx.x * BN;
  const int wave = tid >> 6, lane = tid & 63;
  const int wm = (wave >> 1) * 64, wn = (wave & 1) * 64;
  const int lr = lane & 15, lq = lane >> 4;

  f32x4 acc[4][4];
#pragma unroll
  for (int i = 0; i < 4; i++)
#pragma unroll
    for (int j = 0; j < 4; j++) { f32x4 z = {0.f,0.f,0.f,0.f}; acc[i][j] = z; }

  for (int k0 = 0; k0 < K; k0 += BKK) {
#pragma unroll
    for (int i = 0; i < 4; i++) {
      int c = tid + i * 256;           // 1024 chunks of 8 elements
      int row = c >> 3, cc = (c & 7) * 8;
      uint4 va = *(const uint4*)(A + (size_t)(bm + row) * K + k0 + cc);
      *(uint4*)&sA[row * LDK + cc] = va;
      if (f == 0) {
        uint4 vb = *(const uint4*)((const u16*)B + (size_t)(bn + row) * K + k0 + cc);
        *(uint4*)&sB[row * LDK + cc] = vb;
      } else {
        const float* Bf = (const float*)B + (size_t)(bn + row) * K + k0 + cc;
        uint4 lo = *(const uint4*)(Bf);
        uint4 hi = *(const uint4*)(Bf + 4);
        union { u32 i; float fv; } c0, c1, c2, c3, c4, c5, c6, c7;
        c0.i = lo.x; c1.i = lo.y; c2.i = lo.z; c3.i = lo.w;
        c4.i = hi.x; c5.i = hi.y; c6.i = hi.z; c7.i = hi.w;
        uint4 pb;
        pb.x = packbf(c0.fv, c1.fv); pb.y = packbf(c2.fv, c3.fv);
        pb.z = packbf(c4.fv, c5.fv); pb.w = packbf(c6.fv, c7.fv);
        *(uint4*)&sB[row * LDK + cc] = pb;
      }
    }
    __syncthreads();
    // MFMA 16x16x32 consumes K=32/call (k = (lane>>4)*8 + j); step kk by 32.
#pragma unroll
    for (int kk = 0; kk < BKK; kk += 32) {
      bf16x8 af[4], bfr[4];
#pragma unroll
      for (int i = 0; i < 4; i++)
        af[i] = *(const bf16x8*)&sA[(wm + i * 16 + lr) * LDK + kk + lq * 8];
#pragma unroll
      for (int i = 0; i < 4; i++)
        bfr[i] = *(const bf16x8*)&sB[(wn + i * 16 + lr) * LDK + kk + lq * 8];
#pragma unroll
      for (int i = 0; i < 4; i++)
#pragma unroll
        for (int j = 0; j < 4; j++)
          acc[i][j] = __builtin_amdgcn_mfma_f32_16x16x32_bf16(af[i], bfr[j], acc[i][j], 0, 0, 0);
    }
    __syncthreads();
  }

#pragma unroll
  for (int i = 0; i < 4; i++) {
#pragma unroll
    for (int j = 0; j < 4; j++) {
#pragma unroll
      for (int e = 0; e < 4; e++) {
        int row = bm + wm + i * 16 + lq * 4 + e;   // C/D: row=(lane>>4)*4+reg
        int col = bn + wn + j * 16 + lr;           //      col=lane&15
        size_t idx = (size_t)row * N + col;
        float v = acc[i][j][e];
        if (EPI == 0) {
          ((u16*)Cout)[idx] = f2bf(v);
        } else if (EPI == 1) {
          float rv = f ? ((const float*)R)[idx] : bf2f(((const u16*)R)[idx]);
          ((float*)Cout)[idx] = v + rv;
        } else if (EPI == 2) {
          float s = v + ((const float*)R)[idx];
          if (f) ((float*)Cout)[idx] = s;
          else   ((u16*)Cout)[idx] = f2bf(s);
        } else {
          float g = bf2f(((const u16*)R)[idx]);
          float inner = g / (1.f + __expf(-g)) * v;
          ((u16*)Cout)[idx] = f2bf(inner);
        }
      }
    }
  }
}

// ---------------------------------------------------------------------------
// RMSNorm, D=2048, one block/token. XSRC 0: x from d_in (dual dtype),
// XSRC 1: fp32 workspace (x1). Weight w is d_in: dual dtype.
// ---------------------------------------------------------------------------
template<int XSRC>
__global__ __launch_bounds__(256)
void rmsnorm_k(const void* __restrict__ xin, const void* __restrict__ w,
               u16* __restrict__ out, const u32* __restrict__ dflag)
{
  const u32 f = *dflag;
  const int n = blockIdx.x, tid = threadIdx.x;
  float v[8]; float ss = 0.f;
#pragma unroll
  for (int i = 0; i < 8; i++) {
    int d = i * 256 + tid;
    float xv;
    if (XSRC == 1)      xv = ((const float*)xin)[(size_t)n * 2048 + d];
    else if (f)         xv = ((const float*)xin)[(size_t)n * 2048 + d];
    else                xv = bf2f(((const u16*)xin)[(size_t)n * 2048 + d]);
    v[i] = xv; ss += xv * xv;
  }
#pragma unroll
  for (int o = 32; o >= 1; o >>= 1) ss += __shfl_xor(ss, o, 64);
  __shared__ float red[4];
  if ((tid & 63) == 0) red[tid >> 6] = ss;
  __syncthreads();
  float tot = red[0] + red[1] + red[2] + red[3];
  float rms = rsqrtf(tot * (1.f / 2048.f) + 1e-5f);
#pragma unroll
  for (int i = 0; i < 8; i++) {
    int d = i * 256 + tid;
    float wv = f ? ((const float*)w)[d] : bf2f(((const u16*)w)[d]);
    out[(size_t)n * 2048 + d] = f2bf(v[i] * rms * wv);
  }
}

// ---------------------------------------------------------------------------
// QKV stage 2: out[b,h,t,d] = sum_r xr[n, h*48+r] * Us[h,d,r], optional RoPE.
// xr is ws bf16; Us is d_in (dual dtype).
// ---------------------------------------------------------------------------
template<int ROPE>
__global__ __launch_bounds__(256)
void qkv2_k(const u16* __restrict__ xr, const void* __restrict__ Us,
            const int* __restrict__ pos, u16* __restrict__ out, int NH,
            const u32* __restrict__ dflag)
{
  const u32 f = *dflag;
  const int h = blockIdx.y;
  const int tid = threadIdx.x;
  const int n = blockIdx.x * 8 + (tid >> 5);
  const int j = tid & 31;
  const u16* xrow = xr + (size_t)n * (NH * 48) + h * 48;
  float a = 0.f, b = 0.f;
  if (f == 0) {
    const u16* U = (const u16*)Us + (size_t)h * 64 * 48;
#pragma unroll
    for (int r = 0; r < 48; r++) {
      float xv = bf2f(xrow[r]);
      a += xv * bf2f(U[j * 48 + r]);
      b += xv * bf2f(U[(j + 32) * 48 + r]);
    }
  } else {
    const float* U = (const float*)Us + (size_t)h * 64 * 48;
#pragma unroll
    for (int r = 0; r < 48; r++) {
      float xv = bf2f(xrow[r]);
      a += xv * U[j * 48 + r];
      b += xv * U[(j + 32) * 48 + r];
    }
  }
  const int t = n & 1023, bb = n >> 10;
  float olo, ohi;
  if (ROPE) {
    float p = (float)pos[t];
    float inv_lo = powf(10000.f, -(float)(2 * (j >> 1)) * (1.f / 64.f));
    float inv_hi = powf(10000.f, -(float)(2 * (16 + (j >> 1))) * (1.f / 64.f));
    float sl, cl, sh, ch;
    sincosf(p * inv_lo, &sl, &cl);
    sincosf(p * inv_hi, &sh, &ch);
    olo = a * cl - b * sl;
    ohi = b * ch + a * sh;
  } else { olo = a; ohi = b; }
  size_t ob = ((size_t)(bb * NH + h) * 1024 + t) * 64;
  out[ob + j] = f2bf(olo);
  out[ob + j + 32] = f2bf(ohi);
}

// ---------------------------------------------------------------------------
// Flash attention (causal, GQA 32q/8kv, DH=64, T=1024), online softmax.
// All operands are ws bf16 — no dtype flag needed.
// ---------------------------------------------------------------------------
__global__ __launch_bounds__(256)
void flash_k(const u16* __restrict__ Q, const u16* __restrict__ K,
             const u16* __restrict__ V, u16* __restrict__ O)
{
  __shared__ u32 sK[128 * 33];
  __shared__ u32 sV[128 * 33];
  __shared__ u16 sQ[16 * 72];
  __shared__ float sP[16 * 128];
  const int bh = blockIdx.x;
  const int b = bh >> 5, h = bh & 31, hk = h >> 2;
  const int t0 = blockIdx.y << 4;
  const int tid = threadIdx.x, wave = tid >> 6, lane = tid & 63;
  const u16* Qb = Q + ((size_t)bh * 1024 + t0) * 64;
  const u16* Kb = K + ((size_t)(b * 8 + hk) * 1024) * 64;
  const u16* Vb = V + ((size_t)(b * 8 + hk) * 1024) * 64;

  if (tid < 128) {
    int row = tid >> 3, cc = (tid & 7) * 8;
    uint4 v = *(const uint4*)(Qb + row * 64 + cc);
    *(uint4*)&sQ[row * 72 + cc] = v;
  }

  float m[4], l[4], o[4];
#pragma unroll
  for (int r = 0; r < 4; r++) { m[r] = -3.0e38f; l[r] = 0.f; o[r] = 0.f; }

  const int ntiles = ((t0 + 15) >> 7) + 1;
  for (int st = 0; st < ntiles; st++) {
    const u16* Kt = Kb + (size_t)st * 128 * 64;
    const u16* Vt = Vb + (size_t)st * 128 * 64;
    __syncthreads();
#pragma unroll
    for (int i = 0; i < 4; i++) {
      int c = tid + i * 256;
      int row = c >> 3, w0 = (c & 7) * 4;
      uint4 kv = *(const uint4*)(Kt + row * 64 + w0 * 2);
      uint4 vv = *(const uint4*)(Vt + row * 64 + w0 * 2);
      int base = row * 33 + w0;
      sK[base + 0] = kv.x; sK[base + 1] = kv.y; sK[base + 2] = kv.z; sK[base + 3] = kv.w;
      sV[base + 0] = vv.x; sV[base + 1] = vv.y; sV[base + 2] = vv.z; sV[base + 3] = vv.w;
    }
    __syncthreads();

    float sc[4][2];
#pragma unroll
    for (int r = 0; r < 4; r++) { sc[r][0] = 0.f; sc[r][1] = 0.f; }
#pragma unroll 4
    for (int d2 = 0; d2 < 32; d2++) {
      u32 k0 = sK[lane * 33 + d2];
      u32 k1 = sK[(64 + lane) * 33 + d2];
      float k0l = bf2f((u16)k0), k0h = bf2f((u16)(k0 >> 16));
      float k1l = bf2f((u16)k1), k1h = bf2f((u16)(k1 >> 16));
#pragma unroll
      for (int r = 0; r < 4; r++) {
        u32 q = *(const u32*)&sQ[(wave * 4 + r) * 72 + d2 * 2];
        float ql = bf2f((u16)q), qh = bf2f((u16)(q >> 16));
        sc[r][0] += ql * k0l + qh * k0h;
        sc[r][1] += ql * k1l + qh * k1h;
      }
    }

    const int s_base = st << 7;
#pragma unroll
    for (int r = 0; r < 4; r++) {
      int trow = t0 + wave * 4 + r;
      float s0 = sc[r][0] * 0.125f, s1 = sc[r][1] * 0.125f;
      if (s_base + lane > trow)      s0 = -1e30f;
      if (s_base + 64 + lane > trow) s1 = -1e30f;
      float tm = fmaxf(s0, s1);
#pragma unroll
      for (int off = 32; off >= 1; off >>= 1) tm = fmaxf(tm, __shfl_xor(tm, off, 64));
      float mnew = fmaxf(m[r], tm);
      float alpha = __expf(m[r] - mnew);
      float p0 = __expf(s0 - mnew);
      float p1 = __expf(s1 - mnew);
      float ts = p0 + p1;
#pragma unroll
      for (int off = 32; off >= 1; off >>= 1) ts += __shfl_xor(ts, off, 64);
      l[r] = l[r] * alpha + ts;
      o[r] *= alpha;
      m[r] = mnew;
      sP[(wave * 4 + r) * 128 + lane] = p0;
      sP[(wave * 4 + r) * 128 + 64 + lane] = p1;
    }

#pragma unroll 2
    for (int s = 0; s < 128; s++) {
      u32 vw = sV[s * 33 + (lane >> 1)];
      float vv = bf2f((u16)((lane & 1) ? (vw >> 16) : (vw & 0xffffu)));
#pragma unroll
      for (int r = 0; r < 4; r++)
        o[r] += sP[(wave * 4 + r) * 128 + s] * vv;
    }
  }

#pragma unroll
  for (int r = 0; r < 4; r++) {
    int trow = t0 + wave * 4 + r;
    size_t idx = ((size_t)(b * 1024 + trow)) * 2048 + h * 64 + lane;
    O[idx] = f2bf(o[r] / l[r]);
  }
}

// ---------------------------------------------------------------------------
// Workspace (73 MB + flag):
//  [0,16)   x1 fp32 residual               live 6-12
//  [16,48)  gate/inner (32MB)              live 9-11; earlier: h1@16(1-2),
//           attn@24(4-5), qb@32(3-4), kb@40, vb@42, ar@44(5-6)
//  [48,65)  xr_q@48(2-3), xr_k@54, xr_v@55.5, h2@57(7-8); dr@48(11-12)
//  [65,73)  gr@65, ur@69 (8-9)
//  @73MB    u32 dtype flag
// ---------------------------------------------------------------------------
extern "C" void kernel_launch(void* const* d_in, const int* in_sizes, int n_in,
                              void* d_out, int out_size, void* d_ws, size_t ws_size,
                              hipStream_t stream)
{
  const void* x    = d_in[0];
  const int* pos   = (const int*)d_in[1];
  const void* ln1w = d_in[2];
  const void* ln2w = d_in[3];
  const void* qUs  = d_in[4];
  const void* qV   = d_in[5];
  const void* kUs  = d_in[6];
  const void* kV   = d_in[7];
  const void* vUs  = d_in[8];
  const void* vV   = d_in[9];
  const void* oUs  = d_in[10];
  const void* oV   = d_in[11];
  const void* gUs  = d_in[12];
  const void* gV   = d_in[13];
  const void* uUs  = d_in[14];
  const void* uV   = d_in[15];
  const void* dUs  = d_in[16];
  const void* dV   = d_in[17];

  char* ws = (char*)d_ws;
  const size_t MB = 1048576;
  float* x1   = (float*)(ws + 0 * MB);
  u16*   gate = (u16*)  (ws + 16 * MB);
  u16*   h1   = (u16*)  (ws + 16 * MB);
  u16*   attn = (u16*)  (ws + 24 * MB);
  u16*   qb   = (u16*)  (ws + 32 * MB);
  u16*   kb   = (u16*)  (ws + 40 * MB);
  u16*   vb   = (u16*)  (ws + 42 * MB);
  u16*   ar   = (u16*)  (ws + 44 * MB);
  u16*   xr_q = (u16*)  (ws + 48 * MB);
  u16*   dr   = (u16*)  (ws + 48 * MB);
  u16*   xr_k = (u16*)  (ws + 54 * MB);
  u16*   xr_v = (u16*)  (ws + 55 * MB + 524288);
  u16*   h2   = (u16*)  (ws + 57 * MB);
  u16*   gr   = (u16*)  (ws + 65 * MB);
  u16*   ur   = (u16*)  (ws + 69 * MB);
  u32*   flag = (u32*)  (ws + 73 * MB);

  dim3 blk(256);

  detect_k<<<1, 64, 0, stream>>>((const u32*)ln1w, flag);

  rmsnorm_k<0><<<2048, blk, 0, stream>>>(x, ln1w, h1, flag);                                  // 1

  gemm_bt<0><<<dim3(12, 16), blk, 0, stream>>>(h1, qV, xr_q, nullptr, 2048, 1536, 2048, flag);// 2
  gemm_bt<0><<<dim3(3, 16),  blk, 0, stream>>>(h1, kV, xr_k, nullptr, 2048, 384, 2048, flag);
  gemm_bt<0><<<dim3(3, 16),  blk, 0, stream>>>(h1, vV, xr_v, nullptr, 2048, 384, 2048, flag);

  qkv2_k<1><<<dim3(256, 32), blk, 0, stream>>>(xr_q, qUs, pos, qb, 32, flag);                 // 3
  qkv2_k<1><<<dim3(256, 8),  blk, 0, stream>>>(xr_k, kUs, pos, kb, 8, flag);
  qkv2_k<0><<<dim3(256, 8),  blk, 0, stream>>>(xr_v, vUs, pos, vb, 8, flag);

  flash_k<<<dim3(64, 64), blk, 0, stream>>>(qb, kb, vb, attn);                                // 4

  gemm_bt<0><<<dim3(8, 16),  blk, 0, stream>>>(attn, oV, ar, nullptr, 2048, 1024, 2048, flag);// 5
  gemm_bt<1><<<dim3(16, 16), blk, 0, stream>>>(ar, oUs, x1, x, 2048, 2048, 1024, flag);       // 6

  rmsnorm_k<1><<<2048, blk, 0, stream>>>(x1, ln2w, h2, flag);                                 // 7

  gemm_bt<0><<<dim3(8, 16),  blk, 0, stream>>>(h2, gV, gr, nullptr, 2048, 1024, 2048, flag);  // 8
  gemm_bt<0><<<dim3(8, 16),  blk, 0, stream>>>(h2, uV, ur, nullptr, 2048, 1024, 2048, flag);
  gemm_bt<0><<<dim3(64, 16), blk, 0, stream>>>(gr, gUs, gate, nullptr, 2048, 8192, 1024, flag);// 9a
  gemm_bt<3><<<dim3(64, 16), blk, 0, stream>>>(ur, uUs, gate, gate, 2048, 8192, 1024, flag);  // 9b (fused silu*up)

  gemm_bt<0><<<dim3(8, 16),  blk, 0, stream>>>(gate, dV, dr, nullptr, 2048, 1024, 8192, flag);// 11
  gemm_bt<2><<<dim3(16, 16), blk, 0, stream>>>(dr, dUs, d_out, x1, 2048, 2048, 1024, flag);   // 12
}

// Round 4
// 1089.149 us; speedup vs baseline: 2.0805x; 2.0805x over previous
//
#include <hip/hip_runtime.h>

typedef unsigned short u16;
typedef unsigned int u32;
typedef unsigned long long u64;

typedef __bf16 bf16x8 __attribute__((ext_vector_type(8)));
typedef float f32x4 __attribute__((ext_vector_type(4)));

__device__ __forceinline__ float bf2f(u16 u) {
  union { u32 i; float f; } v; v.i = ((u32)u) << 16; return v.f;
}
__device__ __forceinline__ u16 f2bf(float f) {
  union { float f; u32 i; } v; v.f = f;
  u32 r = v.i + 0x7fff + ((v.i >> 16) & 1);
  return (u16)(r >> 16);
}
__device__ __forceinline__ u32 packbf(float a, float b) {
  return (u32)f2bf(a) | ((u32)f2bf(b) << 16);
}

// Detect input dtype from ln1_w (all ones): bf16 word = 0x3F803F80, fp32 = 0x3F800000.
__global__ void detect_k(const u32* __restrict__ w, u32* __restrict__ flag) {
  if (threadIdx.x == 0 && blockIdx.x == 0)
    *flag = (w[0] == 0x3F803F80u) ? 0u : 1u;
}

// ---------------------------------------------------------------------------
// Weight convert: all 16 weight tensors -> bf16 copies in ws (fp32 source:
// convert; bf16 source: straight copy). Block = 2048 elems; all sizes are
// exact multiples of 2048 (no tail guards). 19786 blocks total.
// ---------------------------------------------------------------------------
struct CvtTab {
  const void* src[16];
  u64 doff[16];      // element offset into wbase
  u32 bstart[16];    // first block id of tensor
};

__global__ __launch_bounds__(256)
void convert_k(CvtTab tab, u16* __restrict__ wbase, const u32* __restrict__ dflag)
{
  const u32 f = *dflag;
  const int blk = blockIdx.x;
  int t = 15;
#pragma unroll
  for (int i = 15; i >= 1; i--) if (blk < (int)tab.bstart[i]) t = i - 1;
  const u64 eoff = (u64)(blk - tab.bstart[t]) * 2048 + threadIdx.x * 8;
  u16* dst = wbase + tab.doff[t] + eoff;
  if (f == 0) {
    uint4 v = *(const uint4*)((const u16*)tab.src[t] + eoff);
    *(uint4*)dst = v;
  } else {
    const float* s = (const float*)tab.src[t] + eoff;
    uint4 lo = *(const uint4*)s;
    uint4 hi = *(const uint4*)(s + 4);
    union { u32 i; float fv; } c0,c1,c2,c3,c4,c5,c6,c7;
    c0.i = lo.x; c1.i = lo.y; c2.i = lo.z; c3.i = lo.w;
    c4.i = hi.x; c5.i = hi.y; c6.i = hi.z; c7.i = hi.w;
    uint4 pb;
    pb.x = packbf(c0.fv, c1.fv); pb.y = packbf(c2.fv, c3.fv);
    pb.z = packbf(c4.fv, c5.fv); pb.w = packbf(c6.fv, c7.fv);
    *(uint4*)dst = pb;
  }
}

// ---------------------------------------------------------------------------
// bf16 MFMA GEMM: C[.., ldc] = A[.., lda] * B[N,K]^T (B row stride = K).
// A, B always bf16. TILE = 128 (4 waves x 4x4 frags) or 64 (4 waves x 2x2).
// EPI 0: store bf16.
// EPI 1: store fp32 C = acc + R (dual-dtype d_in residual, flag).
// EPI 2: final: store (flag? fp32 : bf16) C = acc + fp32 R.
// EPI 3: fused SwiGLU: store bf16 C = silu(bf16 R[idx]) * acc (R may == Cout).
// ---------------------------------------------------------------------------
#define BKK 64
#define LDK 72  // padded LDS row stride in u16

template<int EPI, int TILE>
__global__ __launch_bounds__(256)
void gemm_bt(const u16* __restrict__ A, const u16* __restrict__ B,
             void* Cout, const void* R,
             int K, int lda, int ldc, const u32* __restrict__ dflag)
{
  constexpr int WT = TILE / 2;      // wave quadrant
  constexpr int NF = TILE / 32;     // 16x16 frags per wave dim
  constexpr int ITER = TILE / 32;   // staging iterations (TILE*8 chunks / 256)
  __shared__ u16 sA[TILE * LDK];
  __shared__ u16 sB[TILE * LDK];
  const u32 f = *dflag;
  const int tid  = threadIdx.x;
  const int bm   = blockIdx.y * TILE;
  const int bn   = blockIdx.x * TILE;
  const int wave = tid >> 6, lane = tid & 63;
  const int wm = (wave >> 1) * WT, wn = (wave & 1) * WT;
  const int lr = lane & 15, lq = lane >> 4;

  f32x4 acc[NF][NF];
#pragma unroll
  for (int i = 0; i < NF; i++)
#pragma unroll
    for (int j = 0; j < NF; j++) { f32x4 z = {0.f,0.f,0.f,0.f}; acc[i][j] = z; }

  for (int k0 = 0; k0 < K; k0 += BKK) {
#pragma unroll
    for (int i = 0; i < ITER; i++) {
      int c = tid + i * 256;           // chunk of 8 elems
      int row = c >> 3, cc = (c & 7) * 8;
      uint4 va = *(const uint4*)(A + (size_t)(bm + row) * lda + k0 + cc);
      *(uint4*)&sA[row * LDK + cc] = va;
      uint4 vb = *(const uint4*)(B + (size_t)(bn + row) * K + k0 + cc);
      *(uint4*)&sB[row * LDK + cc] = vb;
    }
    __syncthreads();
    // MFMA 16x16x32 consumes K=32/call (k = (lane>>4)*8 + j); step kk by 32.
#pragma unroll
    for (int kk = 0; kk < BKK; kk += 32) {
      bf16x8 af[NF], bfr[NF];
#pragma unroll
      for (int i = 0; i < NF; i++)
        af[i] = *(const bf16x8*)&sA[(wm + i * 16 + lr) * LDK + kk + lq * 8];
#pragma unroll
      for (int i = 0; i < NF; i++)
        bfr[i] = *(const bf16x8*)&sB[(wn + i * 16 + lr) * LDK + kk + lq * 8];
#pragma unroll
      for (int i = 0; i < NF; i++)
#pragma unroll
        for (int j = 0; j < NF; j++)
          acc[i][j] = __builtin_amdgcn_mfma_f32_16x16x32_bf16(af[i], bfr[j], acc[i][j], 0, 0, 0);
    }
    __syncthreads();
  }

#pragma unroll
  for (int i = 0; i < NF; i++) {
#pragma unroll
    for (int j = 0; j < NF; j++) {
#pragma unroll
      for (int e = 0; e < 4; e++) {
        int row = bm + wm + i * 16 + lq * 4 + e;   // C/D: row=(lane>>4)*4+reg
        int col = bn + wn + j * 16 + lr;           //      col=lane&15
        size_t idx = (size_t)row * ldc + col;
        float v = acc[i][j][e];
        if (EPI == 0) {
          ((u16*)Cout)[idx] = f2bf(v);
        } else if (EPI == 1) {
          float rv = f ? ((const float*)R)[idx] : bf2f(((const u16*)R)[idx]);
          ((float*)Cout)[idx] = v + rv;
        } else if (EPI == 2) {
          float s = v + ((const float*)R)[idx];
          if (f) ((float*)Cout)[idx] = s;
          else   ((u16*)Cout)[idx] = f2bf(s);
        } else {
          float g = bf2f(((const u16*)R)[idx]);
          float inner = g / (1.f + __expf(-g)) * v;
          ((u16*)Cout)[idx] = f2bf(inner);
        }
      }
    }
  }
}

// ---------------------------------------------------------------------------
// RMSNorm, D=2048. XSRC 0: x from d_in (dual dtype via flag), 1: fp32 ws.
// Weight w is ws bf16 (pre-converted).
// ---------------------------------------------------------------------------
template<int XSRC>
__global__ __launch_bounds__(256)
void rmsnorm_k(const void* __restrict__ xin, const u16* __restrict__ w,
               u16* __restrict__ out, const u32* __restrict__ dflag)
{
  const u32 f = *dflag;
  const int n = blockIdx.x, tid = threadIdx.x;
  float v[8]; float ss = 0.f;
#pragma unroll
  for (int i = 0; i < 8; i++) {
    int d = i * 256 + tid;
    float xv;
    if (XSRC == 1)      xv = ((const float*)xin)[(size_t)n * 2048 + d];
    else if (f)         xv = ((const float*)xin)[(size_t)n * 2048 + d];
    else                xv = bf2f(((const u16*)xin)[(size_t)n * 2048 + d]);
    v[i] = xv; ss += xv * xv;
  }
#pragma unroll
  for (int o = 32; o >= 1; o >>= 1) ss += __shfl_xor(ss, o, 64);
  __shared__ float red[4];
  if ((tid & 63) == 0) red[tid >> 6] = ss;
  __syncthreads();
  float tot = red[0] + red[1] + red[2] + red[3];
  float rms = rsqrtf(tot * (1.f / 2048.f) + 1e-5f);
#pragma unroll
  for (int i = 0; i < 8; i++) {
    int d = i * 256 + tid;
    out[(size_t)n * 2048 + d] = f2bf(v[i] * rms * bf2f(w[d]));
  }
}

// ---------------------------------------------------------------------------
// QKV stage 2: out[b,h,t,d] = sum_r xr[n, h*48+r] * Us[h,d,r], optional RoPE.
// xr base already includes column offset; row stride = XS. Us is ws bf16.
// ---------------------------------------------------------------------------
template<int ROPE>
__global__ __launch_bounds__(256)
void qkv2_k(const u16* __restrict__ xr, const u16* __restrict__ Us,
            const int* __restrict__ pos, u16* __restrict__ out, int NH, int XS)
{
  const int h = blockIdx.y;
  const int tid = threadIdx.x;
  const int n = blockIdx.x * 8 + (tid >> 5);
  const int j = tid & 31;
  const u16* xrow = xr + (size_t)n * XS + h * 48;
  const u16* U = Us + (size_t)h * 64 * 48;
  float a = 0.f, b = 0.f;
#pragma unroll
  for (int r = 0; r < 48; r++) {
    float xv = bf2f(xrow[r]);
    a += xv * bf2f(U[j * 48 + r]);
    b += xv * bf2f(U[(j + 32) * 48 + r]);
  }
  const int t = n & 1023, bb = n >> 10;
  float olo, ohi;
  if (ROPE) {
    float p = (float)pos[t];
    float inv_lo = powf(10000.f, -(float)(2 * (j >> 1)) * (1.f / 64.f));
    float inv_hi = powf(10000.f, -(float)(2 * (16 + (j >> 1))) * (1.f / 64.f));
    float sl, cl, sh, ch;
    sincosf(p * inv_lo, &sl, &cl);
    sincosf(p * inv_hi, &sh, &ch);
    olo = a * cl - b * sl;
    ohi = b * ch + a * sh;
  } else { olo = a; ohi = b; }
  size_t ob = ((size_t)(bb * NH + h) * 1024 + t) * 64;
  out[ob + j] = f2bf(olo);
  out[ob + j + 32] = f2bf(ohi);
}

// ---------------------------------------------------------------------------
// Flash attention (causal, GQA 32q/8kv, DH=64, T=1024), online softmax.
// ---------------------------------------------------------------------------
__global__ __launch_bounds__(256)
void flash_k(const u16* __restrict__ Q, const u16* __restrict__ K,
             const u16* __restrict__ V, u16* __restrict__ O)
{
  __shared__ u32 sK[128 * 33];
  __shared__ u32 sV[128 * 33];
  __shared__ u16 sQ[16 * 72];
  __shared__ float sP[16 * 128];
  const int bh = blockIdx.x;
  const int b = bh >> 5, h = bh & 31, hk = h >> 2;
  const int t0 = blockIdx.y << 4;
  const int tid = threadIdx.x, wave = tid >> 6, lane = tid & 63;
  const u16* Qb = Q + ((size_t)bh * 1024 + t0) * 64;
  const u16* Kb = K + ((size_t)(b * 8 + hk) * 1024) * 64;
  const u16* Vb = V + ((size_t)(b * 8 + hk) * 1024) * 64;

  if (tid < 128) {
    int row = tid >> 3, cc = (tid & 7) * 8;
    uint4 v = *(const uint4*)(Qb + row * 64 + cc);
    *(uint4*)&sQ[row * 72 + cc] = v;
  }

  float m[4], l[4], o[4];
#pragma unroll
  for (int r = 0; r < 4; r++) { m[r] = -3.0e38f; l[r] = 0.f; o[r] = 0.f; }

  const int ntiles = ((t0 + 15) >> 7) + 1;
  for (int st = 0; st < ntiles; st++) {
    const u16* Kt = Kb + (size_t)st * 128 * 64;
    const u16* Vt = Vb + (size_t)st * 128 * 64;
    __syncthreads();
#pragma unroll
    for (int i = 0; i < 4; i++) {
      int c = tid + i * 256;
      int row = c >> 3, w0 = (c & 7) * 4;
      uint4 kv = *(const uint4*)(Kt + row * 64 + w0 * 2);
      uint4 vv = *(const uint4*)(Vt + row * 64 + w0 * 2);
      int base = row * 33 + w0;
      sK[base + 0] = kv.x; sK[base + 1] = kv.y; sK[base + 2] = kv.z; sK[base + 3] = kv.w;
      sV[base + 0] = vv.x; sV[base + 1] = vv.y; sV[base + 2] = vv.z; sV[base + 3] = vv.w;
    }
    __syncthreads();

    float sc[4][2];
#pragma unroll
    for (int r = 0; r < 4; r++) { sc[r][0] = 0.f; sc[r][1] = 0.f; }
#pragma unroll 4
    for (int d2 = 0; d2 < 32; d2++) {
      u32 k0 = sK[lane * 33 + d2];
      u32 k1 = sK[(64 + lane) * 33 + d2];
      float k0l = bf2f((u16)k0), k0h = bf2f((u16)(k0 >> 16));
      float k1l = bf2f((u16)k1), k1h = bf2f((u16)(k1 >> 16));
#pragma unroll
      for (int r = 0; r < 4; r++) {
        u32 q = *(const u32*)&sQ[(wave * 4 + r) * 72 + d2 * 2];
        float ql = bf2f((u16)q), qh = bf2f((u16)(q >> 16));
        sc[r][0] += ql * k0l + qh * k0h;
        sc[r][1] += ql * k1l + qh * k1h;
      }
    }

    const int s_base = st << 7;
#pragma unroll
    for (int r = 0; r < 4; r++) {
      int trow = t0 + wave * 4 + r;
      float s0 = sc[r][0] * 0.125f, s1 = sc[r][1] * 0.125f;
      if (s_base + lane > trow)      s0 = -1e30f;
      if (s_base + 64 + lane > trow) s1 = -1e30f;
      float tm = fmaxf(s0, s1);
#pragma unroll
      for (int off = 32; off >= 1; off >>= 1) tm = fmaxf(tm, __shfl_xor(tm, off, 64));
      float mnew = fmaxf(m[r], tm);
      float alpha = __expf(m[r] - mnew);
      float p0 = __expf(s0 - mnew);
      float p1 = __expf(s1 - mnew);
      float ts = p0 + p1;
#pragma unroll
      for (int off = 32; off >= 1; off >>= 1) ts += __shfl_xor(ts, off, 64);
      l[r] = l[r] * alpha + ts;
      o[r] *= alpha;
      m[r] = mnew;
      sP[(wave * 4 + r) * 128 + lane] = p0;
      sP[(wave * 4 + r) * 128 + 64 + lane] = p1;
    }

#pragma unroll 2
    for (int s = 0; s < 128; s++) {
      u32 vw = sV[s * 33 + (lane >> 1)];
      float vv = bf2f((u16)((lane & 1) ? (vw >> 16) : (vw & 0xffffu)));
#pragma unroll
      for (int r = 0; r < 4; r++)
        o[r] += sP[(wave * 4 + r) * 128 + s] * vv;
    }
  }

#pragma unroll
  for (int r = 0; r < 4; r++) {
    int trow = t0 + wave * 4 + r;
    size_t idx = ((size_t)(b * 1024 + trow)) * 2048 + h * 64 + lane;
    O[idx] = f2bf(o[r] / l[r]);
  }
}

// ---------------------------------------------------------------------------
// Workspace (bytes from d_ws; MB = 1<<20):
//  [0,16)MB    x1 fp32 residual        live s6-s12
//  [16,48)MB   gate (32MB, s9a-s11); earlier: h1@16 (s1-2), attn@16 (s4-5),
//              xr_all@24 9MB (s2-3), ar@24 (s5-6), h2@28 (s7-8),
//              qb@33 (s3-4), kb@41, vb@43 (s3-4)
//  [48,56)MB   gr_ur (s8-9b)
//  [56,60)MB   dr (s11-12)
//  [60MB, +81043456)  bf16 weight copies (live whole launch)
//  flag u32 after weights
// ---------------------------------------------------------------------------
extern "C" void kernel_launch(void* const* d_in, const int* in_sizes, int n_in,
                              void* d_out, int out_size, void* d_ws, size_t ws_size,
                              hipStream_t stream)
{
  const void* x    = d_in[0];
  const int* pos   = (const int*)d_in[1];

  char* ws = (char*)d_ws;
  const size_t MB = 1048576;
  float* x1     = (float*)(ws + 0 * MB);
  u16*   gate   = (u16*)  (ws + 16 * MB);
  u16*   h1     = (u16*)  (ws + 16 * MB);
  u16*   attn   = (u16*)  (ws + 16 * MB);
  u16*   xr_all = (u16*)  (ws + 24 * MB);
  u16*   ar     = (u16*)  (ws + 24 * MB);
  u16*   h2     = (u16*)  (ws + 28 * MB);
  u16*   qb     = (u16*)  (ws + 33 * MB);
  u16*   kb     = (u16*)  (ws + 41 * MB);
  u16*   vb     = (u16*)  (ws + 43 * MB);
  u16*   gr_ur  = (u16*)  (ws + 48 * MB);
  u16*   dr     = (u16*)  (ws + 56 * MB);
  u16*   wb     = (u16*)  (ws + 60 * MB);   // weights, 40521728 elems
  u32*   flag   = (u32*)  (ws + 60 * MB + 81043456);

  // weight sub-pointers (element offsets)
  u16* wQKV = wb + 0;          // [2304,2048]: qV|kV|vV
  u16* wGU  = wb + 4718592;    // [2048,2048]: gV|uV
  u16* oVc  = wb + 8912896;
  u16* oUsc = wb + 11010048;
  u16* gUsc = wb + 13107200;
  u16* uUsc = wb + 21495808;
  u16* dVc  = wb + 29884416;
  u16* dUsc = wb + 38273024;
  u16* qUsc = wb + 40370176;
  u16* kUsc = wb + 40468480;
  u16* vUsc = wb + 40493056;
  u16* ln1c = wb + 40517632;
  u16* ln2c = wb + 40519680;

  CvtTab tab;
  const int srcidx[16] = {5, 7, 9, 13, 15, 11, 10, 12, 14, 17, 16, 4, 6, 8, 2, 3};
  const u64 doff[16] = {0, 3145728, 3932160, 4718592, 6815744, 8912896, 11010048,
                        13107200, 21495808, 29884416, 38273024, 40370176,
                        40468480, 40493056, 40517632, 40519680};
  const u32 bstart[16] = {0, 1536, 1920, 2304, 3328, 4352, 5376, 6400, 10496,
                          14592, 18688, 19712, 19760, 19772, 19784, 19785};
  for (int i = 0; i < 16; i++) {
    tab.src[i] = d_in[srcidx[i]];
    tab.doff[i] = doff[i];
    tab.bstart[i] = bstart[i];
  }

  dim3 blk(256);

  detect_k<<<1, 64, 0, stream>>>((const u32*)d_in[2], flag);
  convert_k<<<19786, blk, 0, stream>>>(tab, wb, flag);

  rmsnorm_k<0><<<2048, blk, 0, stream>>>(x, ln1c, h1, flag);                               // s1

  gemm_bt<0,64><<<dim3(36, 32), blk, 0, stream>>>(h1, wQKV, xr_all, nullptr,
                                                  2048, 2048, 2304, flag);                 // s2

  qkv2_k<1><<<dim3(256, 32), blk, 0, stream>>>(xr_all,        qUsc, pos, qb, 32, 2304);    // s3
  qkv2_k<1><<<dim3(256, 8),  blk, 0, stream>>>(xr_all + 1536, kUsc, pos, kb, 8,  2304);
  qkv2_k<0><<<dim3(256, 8),  blk, 0, stream>>>(xr_all + 1920, vUsc, pos, vb, 8,  2304);

  flash_k<<<dim3(64, 64), blk, 0, stream>>>(qb, kb, vb, attn);                             // s4

  gemm_bt<0,64><<<dim3(16, 32), blk, 0, stream>>>(attn, oVc, ar, nullptr,
                                                  2048, 2048, 1024, flag);                 // s5
  gemm_bt<1,64><<<dim3(32, 32), blk, 0, stream>>>(ar, oUsc, x1, x,
                                                  1024, 1024, 2048, flag);                 // s6

  rmsnorm_k<1><<<2048, blk, 0, stream>>>(x1, ln2c, h2, flag);                              // s7

  gemm_bt<0,64><<<dim3(32, 32), blk, 0, stream>>>(h2, wGU, gr_ur, nullptr,
                                                  2048, 2048, 2048, flag);                 // s8
  gemm_bt<0,128><<<dim3(64, 16), blk, 0, stream>>>(gr_ur, gUsc, gate, nullptr,
                                                   1024, 2048, 8192, flag);                // s9a
  gemm_bt<3,128><<<dim3(64, 16), blk, 0, stream>>>(gr_ur + 1024, uUsc, gate, gate,
                                                   1024, 2048, 8192, flag);                // s9b

  gemm_bt<0,64><<<dim3(16, 32), blk, 0, stream>>>(gate, dVc, dr, nullptr,
                                                  8192, 8192, 1024, flag);                 // s11
  gemm_bt<2,64><<<dim3(32, 32), blk, 0, stream>>>(dr, dUsc, d_out, x1,
                                                  1024, 1024, 2048, flag);                 // s12
}

// Round 5
// 805.064 us; speedup vs baseline: 2.8147x; 1.3529x over previous
//
#include <hip/hip_runtime.h>

typedef unsigned short u16;
typedef unsigned int u32;
typedef unsigned long long u64;

typedef __bf16 bf16x8 __attribute__((ext_vector_type(8)));
typedef float f32x4 __attribute__((ext_vector_type(4)));

__device__ __forceinline__ float bf2f(u16 u) {
  union { u32 i; float f; } v; v.i = ((u32)u) << 16; return v.f;
}
__device__ __forceinline__ u16 f2bf(float f) {
  union { float f; u32 i; } v; v.f = f;
  u32 r = v.i + 0x7fff + ((v.i >> 16) & 1);
  return (u16)(r >> 16);
}
__device__ __forceinline__ u32 packbf(float a, float b) {
  return (u32)f2bf(a) | ((u32)f2bf(b) << 16);
}

// Detect input dtype from ln1_w (all ones): bf16 word = 0x3F803F80, fp32 = 0x3F800000.
__global__ void detect_k(const u32* __restrict__ w, u32* __restrict__ flag) {
  if (threadIdx.x == 0 && blockIdx.x == 0)
    *flag = (w[0] == 0x3F803F80u) ? 0u : 1u;
}

// ---------------------------------------------------------------------------
// Weight convert: all 16 weight tensors -> bf16 copies in ws.
// ---------------------------------------------------------------------------
struct CvtTab {
  const void* src[16];
  u64 doff[16];      // element offset into wbase
  u32 bstart[16];    // first block id of tensor
};

__global__ __launch_bounds__(256)
void convert_k(CvtTab tab, u16* __restrict__ wbase, const u32* __restrict__ dflag)
{
  const u32 f = *dflag;
  const int blk = blockIdx.x;
  int t = 15;
#pragma unroll
  for (int i = 15; i >= 1; i--) if (blk < (int)tab.bstart[i]) t = i - 1;
  const u64 eoff = (u64)(blk - tab.bstart[t]) * 2048 + threadIdx.x * 8;
  u16* dst = wbase + tab.doff[t] + eoff;
  if (f == 0) {
    uint4 v = *(const uint4*)((const u16*)tab.src[t] + eoff);
    *(uint4*)dst = v;
  } else {
    const float* s = (const float*)tab.src[t] + eoff;
    uint4 lo = *(const uint4*)s;
    uint4 hi = *(const uint4*)(s + 4);
    union { u32 i; float fv; } c0,c1,c2,c3,c4,c5,c6,c7;
    c0.i = lo.x; c1.i = lo.y; c2.i = lo.z; c3.i = lo.w;
    c4.i = hi.x; c5.i = hi.y; c6.i = hi.z; c7.i = hi.w;
    uint4 pb;
    pb.x = packbf(c0.fv, c1.fv); pb.y = packbf(c2.fv, c3.fv);
    pb.z = packbf(c4.fv, c5.fv); pb.w = packbf(c6.fv, c7.fv);
    *(uint4*)dst = pb;
  }
}

// ---------------------------------------------------------------------------
// bf16 MFMA GEMM: C[.., ldc] = A[.., lda] * B[N,K]^T (B row stride = K).
// TILE = 128 (4 waves x 4x4 frags) or 64 (4 waves x 2x2).
// EPI 0: bf16. EPI 1: fp32 C = acc + R(dual-dtype d_in). EPI 2: final
// (flag? fp32 : bf16) C = acc + fp32 R. EPI 3: bf16 C = silu(R)*acc.
// ---------------------------------------------------------------------------
#define BKK 64
#define LDK 72  // padded LDS row stride in u16

template<int EPI, int TILE>
__global__ __launch_bounds__(256)
void gemm_bt(const u16* __restrict__ A, const u16* __restrict__ B,
             void* Cout, const void* R,
             int K, int lda, int ldc, const u32* __restrict__ dflag)
{
  constexpr int WT = TILE / 2;
  constexpr int NF = TILE / 32;
  constexpr int ITER = TILE / 32;
  __shared__ u16 sA[TILE * LDK];
  __shared__ u16 sB[TILE * LDK];
  const u32 f = *dflag;
  const int tid  = threadIdx.x;
  const int bm   = blockIdx.y * TILE;
  const int bn   = blockIdx.x * TILE;
  const int wave = tid >> 6, lane = tid & 63;
  const int wm = (wave >> 1) * WT, wn = (wave & 1) * WT;
  const int lr = lane & 15, lq = lane >> 4;

  f32x4 acc[NF][NF];
#pragma unroll
  for (int i = 0; i < NF; i++)
#pragma unroll
    for (int j = 0; j < NF; j++) { f32x4 z = {0.f,0.f,0.f,0.f}; acc[i][j] = z; }

  for (int k0 = 0; k0 < K; k0 += BKK) {
#pragma unroll
    for (int i = 0; i < ITER; i++) {
      int c = tid + i * 256;
      int row = c >> 3, cc = (c & 7) * 8;
      uint4 va = *(const uint4*)(A + (size_t)(bm + row) * lda + k0 + cc);
      *(uint4*)&sA[row * LDK + cc] = va;
      uint4 vb = *(const uint4*)(B + (size_t)(bn + row) * K + k0 + cc);
      *(uint4*)&sB[row * LDK + cc] = vb;
    }
    __syncthreads();
#pragma unroll
    for (int kk = 0; kk < BKK; kk += 32) {
      bf16x8 af[NF], bfr[NF];
#pragma unroll
      for (int i = 0; i < NF; i++)
        af[i] = *(const bf16x8*)&sA[(wm + i * 16 + lr) * LDK + kk + lq * 8];
#pragma unroll
      for (int i = 0; i < NF; i++)
        bfr[i] = *(const bf16x8*)&sB[(wn + i * 16 + lr) * LDK + kk + lq * 8];
#pragma unroll
      for (int i = 0; i < NF; i++)
#pragma unroll
        for (int j = 0; j < NF; j++)
          acc[i][j] = __builtin_amdgcn_mfma_f32_16x16x32_bf16(af[i], bfr[j], acc[i][j], 0, 0, 0);
    }
    __syncthreads();
  }

#pragma unroll
  for (int i = 0; i < NF; i++) {
#pragma unroll
    for (int j = 0; j < NF; j++) {
#pragma unroll
      for (int e = 0; e < 4; e++) {
        int row = bm + wm + i * 16 + lq * 4 + e;
        int col = bn + wn + j * 16 + lr;
        size_t idx = (size_t)row * ldc + col;
        float v = acc[i][j][e];
        if (EPI == 0) {
          ((u16*)Cout)[idx] = f2bf(v);
        } else if (EPI == 1) {
          float rv = f ? ((const float*)R)[idx] : bf2f(((const u16*)R)[idx]);
          ((float*)Cout)[idx] = v + rv;
        } else if (EPI == 2) {
          float s = v + ((const float*)R)[idx];
          if (f) ((float*)Cout)[idx] = s;
          else   ((u16*)Cout)[idx] = f2bf(s);
        } else {
          float g = bf2f(((const u16*)R)[idx]);
          float inner = g / (1.f + __expf(-g)) * v;
          ((u16*)Cout)[idx] = f2bf(inner);
        }
      }
    }
  }
}

// ---------------------------------------------------------------------------
// RMSNorm, D=2048. XSRC 0: x from d_in (dual dtype via flag), 1: fp32 ws.
// ---------------------------------------------------------------------------
template<int XSRC>
__global__ __launch_bounds__(256)
void rmsnorm_k(const void* __restrict__ xin, const u16* __restrict__ w,
               u16* __restrict__ out, const u32* __restrict__ dflag)
{
  const u32 f = *dflag;
  const int n = blockIdx.x, tid = threadIdx.x;
  float v[8]; float ss = 0.f;
#pragma unroll
  for (int i = 0; i < 8; i++) {
    int d = i * 256 + tid;
    float xv;
    if (XSRC == 1)      xv = ((const float*)xin)[(size_t)n * 2048 + d];
    else if (f)         xv = ((const float*)xin)[(size_t)n * 2048 + d];
    else                xv = bf2f(((const u16*)xin)[(size_t)n * 2048 + d]);
    v[i] = xv; ss += xv * xv;
  }
#pragma unroll
  for (int o = 32; o >= 1; o >>= 1) ss += __shfl_xor(ss, o, 64);
  __shared__ float red[4];
  if ((tid & 63) == 0) red[tid >> 6] = ss;
  __syncthreads();
  float tot = red[0] + red[1] + red[2] + red[3];
  float rms = rsqrtf(tot * (1.f / 2048.f) + 1e-5f);
#pragma unroll
  for (int i = 0; i < 8; i++) {
    int d = i * 256 + tid;
    out[(size_t)n * 2048 + d] = f2bf(v[i] * rms * bf2f(w[d]));
  }
}

// ---------------------------------------------------------------------------
// QKV stage 2. TRANS=0: out[b,h,t,d]. TRANS=1: out[b,h,d,t] (for V^T).
// ---------------------------------------------------------------------------
template<int ROPE, int TRANS>
__global__ __launch_bounds__(256)
void qkv2_k(const u16* __restrict__ xr, const u16* __restrict__ Us,
            const int* __restrict__ pos, u16* __restrict__ out, int NH, int XS)
{
  const int h = blockIdx.y;
  const int tid = threadIdx.x;
  const int n = blockIdx.x * 8 + (tid >> 5);
  const int j = tid & 31;
  const u16* xrow = xr + (size_t)n * XS + h * 48;
  const u16* U = Us + (size_t)h * 64 * 48;
  float a = 0.f, b = 0.f;
#pragma unroll
  for (int r = 0; r < 48; r++) {
    float xv = bf2f(xrow[r]);
    a += xv * bf2f(U[j * 48 + r]);
    b += xv * bf2f(U[(j + 32) * 48 + r]);
  }
  const int t = n & 1023, bb = n >> 10;
  float olo, ohi;
  if (ROPE) {
    float p = (float)pos[t];
    float inv_lo = powf(10000.f, -(float)(2 * (j >> 1)) * (1.f / 64.f));
    float inv_hi = powf(10000.f, -(float)(2 * (16 + (j >> 1))) * (1.f / 64.f));
    float sl, cl, sh, ch;
    sincosf(p * inv_lo, &sl, &cl);
    sincosf(p * inv_hi, &sh, &ch);
    olo = a * cl - b * sl;
    ohi = b * ch + a * sh;
  } else { olo = a; ohi = b; }
  if (TRANS == 0) {
    size_t ob = ((size_t)(bb * NH + h) * 1024 + t) * 64;
    out[ob + j] = f2bf(olo);
    out[ob + j + 32] = f2bf(ohi);
  } else {
    size_t ob = (size_t)(bb * NH + h) * 64 * 1024;
    out[ob + (size_t)j * 1024 + t] = f2bf(olo);
    out[ob + (size_t)(j + 32) * 1024 + t] = f2bf(ohi);
  }
}

// ---------------------------------------------------------------------------
// MFMA flash attention (causal, GQA 32q/8kv, DH=64, T=1024).
// Block: 64 q-rows (4 waves x 16-row band), key tiles of 128.
// QK^T and P.V on matrix pipe; softmax in C-layout (row = lq*4+e).
// P re-enters PV in A-layout via LDS round-trip. V given TRANSPOSED [d,t].
// ---------------------------------------------------------------------------
__global__ __launch_bounds__(256)
void flash_k(const u16* __restrict__ Q, const u16* __restrict__ K,
             const u16* __restrict__ VT, u16* __restrict__ O)
{
  __shared__ u16 sQ[64 * 72];     //  9216 B
  __shared__ u16 sK[128 * 72];    // 18432 B
  __shared__ u16 sVT[64 * 136];   // 17408 B
  __shared__ u16 sP[64 * 136];    // 17408 B (per-wave-private 16-row bands)
  const int bh = blockIdx.x;
  const int b = bh >> 5, h = bh & 31, hk = h >> 2;
  const int t0 = blockIdx.y << 6;
  const int tid = threadIdx.x, wave = tid >> 6, lane = tid & 63;
  const int lr = lane & 15, lq = lane >> 4;
  const int qr = wave * 16;
  const size_t bhk = (size_t)(b * 8 + hk);
  const u16* Qb = Q + ((size_t)bh * 1024 + t0) * 64;
  const u16* Kb = K + bhk * 1024 * 64;
  const u16* Vb = VT + bhk * 64 * 1024;

  // stage Q [64,64]
#pragma unroll
  for (int i = 0; i < 2; i++) {
    int c = tid + i * 256;
    int row = c >> 3, col = (c & 7) * 8;
    *(uint4*)&sQ[row * 72 + col] = *(const uint4*)(Qb + row * 64 + col);
  }

  f32x4 acc[4];
#pragma unroll
  for (int dt = 0; dt < 4; dt++) { f32x4 z = {0.f,0.f,0.f,0.f}; acc[dt] = z; }
  float m[4], l[4];
#pragma unroll
  for (int e = 0; e < 4; e++) { m[e] = -3.0e38f; l[e] = 0.f; }

  const int ntiles = (t0 >> 7) + 1;
  for (int st = 0; st < ntiles; st++) {
    __syncthreads();   // covers Q staging on iter 0; protects sK/sVT reuse after
#pragma unroll
    for (int i = 0; i < 4; i++) {
      int c = tid + i * 256;
      int row = c >> 3, col = (c & 7) * 8;
      *(uint4*)&sK[row * 72 + col] =
          *(const uint4*)(Kb + (size_t)(st * 128 + row) * 64 + col);
    }
#pragma unroll
    for (int i = 0; i < 4; i++) {
      int c = tid + i * 256;
      int d = c >> 4, t8 = (c & 15) * 8;
      *(uint4*)&sVT[d * 136 + t8] =
          *(const uint4*)(Vb + (size_t)d * 1024 + st * 128 + t8);
    }
    __syncthreads();

    // S = Q.K^T : wave band 16 q-rows x 128 keys (8 col-tiles, 2 k-steps)
    bf16x8 aq0 = *(const bf16x8*)&sQ[(qr + lr) * 72 + lq * 8];
    bf16x8 aq1 = *(const bf16x8*)&sQ[(qr + lr) * 72 + 32 + lq * 8];
    f32x4 sf[8];
#pragma unroll
    for (int nt = 0; nt < 8; nt++) {
      f32x4 z = {0.f,0.f,0.f,0.f};
      bf16x8 bk0 = *(const bf16x8*)&sK[(nt * 16 + lr) * 72 + lq * 8];
      bf16x8 bk1 = *(const bf16x8*)&sK[(nt * 16 + lr) * 72 + 32 + lq * 8];
      z = __builtin_amdgcn_mfma_f32_16x16x32_bf16(aq0, bk0, z, 0, 0, 0);
      z = __builtin_amdgcn_mfma_f32_16x16x32_bf16(aq1, bk1, z, 0, 0, 0);
      sf[nt] = z;
    }

    // online softmax, C-layout: row = lq*4+e, col = nt*16+lr
    const int colbase = st * 128;
#pragma unroll
    for (int e = 0; e < 4; e++) {
      const int row = t0 + qr + lq * 4 + e;
      float tm = -3.0e38f;
#pragma unroll
      for (int nt = 0; nt < 8; nt++) {
        float v = sf[nt][e] * 0.125f;
        if (colbase + nt * 16 + lr > row) v = -1e30f;
        sf[nt][e] = v;
        tm = fmaxf(tm, v);
      }
      tm = fmaxf(tm, __shfl_xor(tm, 1, 64));
      tm = fmaxf(tm, __shfl_xor(tm, 2, 64));
      tm = fmaxf(tm, __shfl_xor(tm, 4, 64));
      tm = fmaxf(tm, __shfl_xor(tm, 8, 64));
      float mnew = fmaxf(m[e], tm);
      float alpha = __expf(m[e] - mnew);
      m[e] = mnew;
      float ts = 0.f;
#pragma unroll
      for (int nt = 0; nt < 8; nt++) {
        float p = __expf(sf[nt][e] - mnew);
        sP[(qr + lq * 4 + e) * 136 + nt * 16 + lr] = f2bf(p);
        ts += p;
      }
      ts += __shfl_xor(ts, 1, 64);
      ts += __shfl_xor(ts, 2, 64);
      ts += __shfl_xor(ts, 4, 64);
      ts += __shfl_xor(ts, 8, 64);
      l[e] = l[e] * alpha + ts;
#pragma unroll
      for (int dt = 0; dt < 4; dt++) acc[dt][e] *= alpha;
    }

    // O += P.V : A = P (band rows, A-layout), B = V^T rows (d), k = keys
#pragma unroll
    for (int kk = 0; kk < 4; kk++) {
      bf16x8 pa = *(const bf16x8*)&sP[(qr + lr) * 136 + kk * 32 + lq * 8];
#pragma unroll
      for (int dt = 0; dt < 4; dt++) {
        bf16x8 bv = *(const bf16x8*)&sVT[(dt * 16 + lr) * 136 + kk * 32 + lq * 8];
        acc[dt] = __builtin_amdgcn_mfma_f32_16x16x32_bf16(pa, bv, acc[dt], 0, 0, 0);
      }
    }
  }

#pragma unroll
  for (int e = 0; e < 4; e++) {
    float inv = 1.f / l[e];
    int t = t0 + qr + lq * 4 + e;
#pragma unroll
    for (int dt = 0; dt < 4; dt++) {
      size_t idx = ((size_t)(b * 1024 + t)) * 2048 + h * 64 + dt * 16 + lr;
      O[idx] = f2bf(acc[dt][e] * inv);
    }
  }
}

// ---------------------------------------------------------------------------
// Workspace: [0,16)MB x1 fp32 | [16,48)MB gate (earlier h1@16, attn@16,
// xr_all@24, ar@24, h2@28, qb@33, kb@41, vbt@43) | [48,56) gr_ur |
// [56,60) dr | [60MB,+81043456) bf16 weights | flag.
// ---------------------------------------------------------------------------
extern "C" void kernel_launch(void* const* d_in, const int* in_sizes, int n_in,
                              void* d_out, int out_size, void* d_ws, size_t ws_size,
                              hipStream_t stream)
{
  const void* x    = d_in[0];
  const int* pos   = (const int*)d_in[1];

  char* ws = (char*)d_ws;
  const size_t MB = 1048576;
  float* x1     = (float*)(ws + 0 * MB);
  u16*   gate   = (u16*)  (ws + 16 * MB);
  u16*   h1     = (u16*)  (ws + 16 * MB);
  u16*   attn   = (u16*)  (ws + 16 * MB);
  u16*   xr_all = (u16*)  (ws + 24 * MB);
  u16*   ar     = (u16*)  (ws + 24 * MB);
  u16*   h2     = (u16*)  (ws + 28 * MB);
  u16*   qb     = (u16*)  (ws + 33 * MB);
  u16*   kb     = (u16*)  (ws + 41 * MB);
  u16*   vbt    = (u16*)  (ws + 43 * MB);
  u16*   gr_ur  = (u16*)  (ws + 48 * MB);
  u16*   dr     = (u16*)  (ws + 56 * MB);
  u16*   wb     = (u16*)  (ws + 60 * MB);
  u32*   flag   = (u32*)  (ws + 60 * MB + 81043456);

  u16* wQKV = wb + 0;          // [2304,2048]: qV|kV|vV
  u16* wGU  = wb + 4718592;    // [2048,2048]: gV|uV
  u16* oVc  = wb + 8912896;
  u16* oUsc = wb + 11010048;
  u16* gUsc = wb + 13107200;
  u16* uUsc = wb + 21495808;
  u16* dVc  = wb + 29884416;
  u16* dUsc = wb + 38273024;
  u16* qUsc = wb + 40370176;
  u16* kUsc = wb + 40468480;
  u16* vUsc = wb + 40493056;
  u16* ln1c = wb + 40517632;
  u16* ln2c = wb + 40519680;

  CvtTab tab;
  const int srcidx[16] = {5, 7, 9, 13, 15, 11, 10, 12, 14, 17, 16, 4, 6, 8, 2, 3};
  const u64 doff[16] = {0, 3145728, 3932160, 4718592, 6815744, 8912896, 11010048,
                        13107200, 21495808, 29884416, 38273024, 40370176,
                        40468480, 40493056, 40517632, 40519680};
  const u32 bstart[16] = {0, 1536, 1920, 2304, 3328, 4352, 5376, 6400, 10496,
                          14592, 18688, 19712, 19760, 19772, 19784, 19785};
  for (int i = 0; i < 16; i++) {
    tab.src[i] = d_in[srcidx[i]];
    tab.doff[i] = doff[i];
    tab.bstart[i] = bstart[i];
  }

  dim3 blk(256);

  detect_k<<<1, 64, 0, stream>>>((const u32*)d_in[2], flag);
  convert_k<<<19786, blk, 0, stream>>>(tab, wb, flag);

  rmsnorm_k<0><<<2048, blk, 0, stream>>>(x, ln1c, h1, flag);                               // s1

  gemm_bt<0,64><<<dim3(36, 32), blk, 0, stream>>>(h1, wQKV, xr_all, nullptr,
                                                  2048, 2048, 2304, flag);                 // s2

  qkv2_k<1,0><<<dim3(256, 32), blk, 0, stream>>>(xr_all,        qUsc, pos, qb, 32, 2304);  // s3
  qkv2_k<1,0><<<dim3(256, 8),  blk, 0, stream>>>(xr_all + 1536, kUsc, pos, kb, 8,  2304);
  qkv2_k<0,1><<<dim3(256, 8),  blk, 0, stream>>>(xr_all + 1920, vUsc, pos, vbt, 8, 2304);

  flash_k<<<dim3(64, 16), blk, 0, stream>>>(qb, kb, vbt, attn);                            // s4

  gemm_bt<0,64><<<dim3(16, 32), blk, 0, stream>>>(attn, oVc, ar, nullptr,
                                                  2048, 2048, 1024, flag);                 // s5
  gemm_bt<1,64><<<dim3(32, 32), blk, 0, stream>>>(ar, oUsc, x1, x,
                                                  1024, 1024, 2048, flag);                 // s6

  rmsnorm_k<1><<<2048, blk, 0, stream>>>(x1, ln2c, h2, flag);                              // s7

  gemm_bt<0,64><<<dim3(32, 32), blk, 0, stream>>>(h2, wGU, gr_ur, nullptr,
                                                  2048, 2048, 2048, flag);                 // s8
  gemm_bt<0,128><<<dim3(64, 16), blk, 0, stream>>>(gr_ur, gUsc, gate, nullptr,
                                                   1024, 2048, 8192, flag);                // s9a
  gemm_bt<3,128><<<dim3(64, 16), blk, 0, stream>>>(gr_ur + 1024, uUsc, gate, gate,
                                                   1024, 2048, 8192, flag);                // s9b

  gemm_bt<0,64><<<dim3(16, 32), blk, 0, stream>>>(gate, dVc, dr, nullptr,
                                                  8192, 8192, 1024, flag);                 // s11
  gemm_bt<2,64><<<dim3(32, 32), blk, 0, stream>>>(dr, dUsc, d_out, x1,
                                                  1024, 1024, 2048, flag);                 // s12
}